// Round 1
// baseline (776.523 us; speedup 1.0000x reference)
//
#include <hip/hip_runtime.h>

#define BATCH 16384
#define N_NEG 10
#define N_DIM 128

__device__ __forceinline__ float log_sigmoid(float x) {
    // stable: min(x,0) - log1p(exp(-|x|))
    return fminf(x, 0.0f) - log1pf(__expf(-fabsf(x)));
}

// One full 64-lane wave per batch element.
// - b is wave-uniform (readfirstlane) -> all 13 embedding indices load via the
//   scalar pipe (s_load), row base addresses are SALU/SGPR, and each row load
//   is global_load_dwordx2 with a single shared lane-offset VGPR.
// - 64 lanes * 8 B = one 512 B embedding row per load instruction (coalesced).
// - ~26 VGPRs of row data in flight vs 52 before -> 8 waves/SIMD occupancy.
__global__ __launch_bounds__(256, 8) void all2vec_kernel(
    const int*   __restrict__ pos_v,
    const int*   __restrict__ pos_u,
    const int*   __restrict__ neg,
    const float* __restrict__ weights,
    const float* __restrict__ emb,
    const float* __restrict__ emb_ctx,
    float*       __restrict__ out)
{
    const int lane = threadIdx.x & 63;
    const int waveInBlock = threadIdx.x >> 6;              // 4 waves / block
    // wave-uniform batch element id, forced into an SGPR
    const int b = __builtin_amdgcn_readfirstlane(blockIdx.x * 4 + waveInBlock);

    const float2* e2 = (const float2*)emb;      // 64 float2 per 128-f row
    const float2* c2 = (const float2*)emb_ctx;

    // wave-uniform index loads -> scalar loads (s_load), SGPR results
    const long long iv = pos_v[b];
    const long long iu = pos_u[b];
    int nidx[N_NEG];
#pragma unroll
    for (int k = 0; k < N_NEG; ++k) nidx[k] = neg[b * N_NEG + k];

    // issue all 13 row loads back-to-back (independent -> max MLP)
    const float2 v  = e2[iv * 64 + lane];
    const float2 ru = e2[iu * 64 + lane];
    const float2 rc = c2[iu * 64 + lane];
    float2 rn[N_NEG];
#pragma unroll
    for (int k = 0; k < N_NEG; ++k)
        rn[k] = c2[(long long)nidx[k] * 64 + lane];

    float acc[12];
    acc[0] = ru.x * v.x + ru.y * v.y;
    acc[1] = rc.x * v.x + rc.y * v.y;
#pragma unroll
    for (int k = 0; k < N_NEG; ++k)
        acc[2 + k] = rn[k].x * v.x + rn[k].y * v.y;

    // full-wave butterfly reduction (mask 32 crosses halves: ds_bpermute/permlane)
#pragma unroll
    for (int j = 0; j < 12; ++j) {
#pragma unroll
        for (int m = 32; m > 0; m >>= 1)
            acc[j] += __shfl_xor(acc[j], m, 64);
    }

    if (lane == 0) {
        const float w = weights[b];
        float negsum = 0.0f;
#pragma unroll
        for (int k = 0; k < N_NEG; ++k)
            negsum += log_sigmoid(-acc[2 + k]);
        out[b]         = w * (-log_sigmoid(acc[0]) - negsum);  // score_1
        out[BATCH + b] = w * (-log_sigmoid(acc[1]) - negsum);  // score_2
    }
}

extern "C" void kernel_launch(void* const* d_in, const int* in_sizes, int n_in,
                              void* d_out, int out_size, void* d_ws, size_t ws_size,
                              hipStream_t stream) {
    const int*   pos_v   = (const int*)d_in[0];
    const int*   pos_u   = (const int*)d_in[1];
    const int*   neg     = (const int*)d_in[2];
    const float* weights = (const float*)d_in[3];
    const float* emb     = (const float*)d_in[4];
    const float* emb_ctx = (const float*)d_in[5];
    float*       out     = (float*)d_out;

    const int waves_total = BATCH;            // 1 batch element per wave
    const int blocks = waves_total / 4;       // 4 waves (256 thr) per block -> 4096
    all2vec_kernel<<<blocks, 256, 0, stream>>>(pos_v, pos_u, neg, weights,
                                               emb, emb_ctx, out);
}